// Round 11
// baseline (125.550 us; speedup 1.0000x reference)
//
#include <hip/hip_runtime.h>
#include <math.h>

#define N_NODES 10000
#define CAP 96             // raw neighbor capacity (true deg ~ mean 32, sd 5.7, +dups)
#define BN_EPS 1e-5f
#define DEG_EPS 1e-8f
#define SHARDS 32

// ---------------- K1: clear cnt + acc (56,576 B contiguous) ----------------
__global__ void __launch_bounds__(256) clear_small(uint4* __restrict__ p, int n16) {
    int t = blockIdx.x * blockDim.x + threadIdx.x;
    if (t < n16) p[t] = make_uint4(0u, 0u, 0u, 0u);
}

// ---------------- K2: scatter append (ONE independent atomic per edge) ----------------
__global__ void __launch_bounds__(256) scatter_append(const int* __restrict__ e, int E,
                                                      int* __restrict__ cnt,
                                                      int* __restrict__ nbr) {
    int t = blockIdx.x * blockDim.x + threadIdx.x;
    if (t < E) {
        int s = e[t];
        int d = e[E + t];
        int slot = atomicAdd(&cnt[s], 1);
        if (slot < CAP) nbr[(size_t)s * CAP + slot] = d;
    }
}

// ---------------- K3: in-register wave dedup + compact + deg/dinv/xs ----------------
__global__ void __launch_bounds__(256) dedup_csr(int* __restrict__ nbr, int* __restrict__ cnt,
                                                 float* __restrict__ dinv,
                                                 const float* __restrict__ x,
                                                 float* __restrict__ xs) {
    int i = blockIdx.x * 4 + (threadIdx.x >> 6);   // one wave per row, 2500 blocks
    int lane = threadIdx.x & 63;
    int c_raw = cnt[i];
    if (c_raw > CAP) c_raw = CAP;
    int c1 = c_raw < 64 ? c_raw : 64;              // chunk1: entries 0..c1-1
    int c2 = c_raw - c1;                           // chunk2: entries 64..c_raw-1 (<=32)
    int* lst = nbr + (size_t)i * CAP;
    int v1 = (lane < c1) ? lst[lane] : -1;
    int v2 = (lane < c2) ? lst[64 + lane] : -2;    // sentinels never match node ids
    bool dup1 = false, dup2 = false;
    for (int k = 0; k < c1; ++k) {                 // wave-uniform trip count
        int v = __shfl(v1, k);
        unsigned long long b = __ballot(v1 == v);
        if (lane == k) dup1 = (b & ((1ull << k) - 1)) != 0;   // earlier equal entry
        dup2 = dup2 || (v2 == v);                  // chunk1 precedes all of chunk2
    }
    for (int k = 0; k < c2; ++k) {
        int v = __shfl(v2, k);
        unsigned long long b = __ballot(v2 == v);
        if (lane == k) dup2 = dup2 || ((b & ((1ull << k) - 1)) != 0);
    }
    bool keep1 = (lane < c1) && !dup1;
    bool keep2 = (lane < c2) && !dup2;
    unsigned long long m1 = __ballot(keep1);
    unsigned long long m2 = __ballot(keep2);
    unsigned long long lt = ((unsigned long long)1 << lane) - 1;
    int n1 = __popcll(m1);
    int deg = n1 + __popcll(m2);
    int pos1 = __popcll(m1 & lt);
    int pos2 = n1 + __popcll(m2 & lt);
    if (keep1) lst[pos1] = v1;                     // values all in regs: safe in-place
    if (keep2) lst[pos2] = v2;
    float di = rsqrtf((float)(deg + 1) + DEG_EPS); // +1 from added identity
    if (lane == 0) { cnt[i] = deg; dinv[i] = di; }
    if (lane < 6) xs[(size_t)i * 6 + lane] = di * x[(size_t)i * 6 + lane];
}

// ---------------- K4: agg1 (dim6, prescaled xs) + GEMM W0 + BN1 shards ----------------
__global__ void __launch_bounds__(256) agg1_gemm_bn(const int* __restrict__ nbr,
                                                    const int* __restrict__ cnt,
                                                    const float* __restrict__ dinv,
                                                    const float* __restrict__ xs,
                                                    const float* __restrict__ W0,
                                                    const float* __restrict__ b0,
                                                    float* __restrict__ h1,
                                                    float* __restrict__ acc) {
    int tid = threadIdx.x;
    int lane = tid & 63;
    int i = blockIdx.x * 4 + (tid >> 6);           // one row per wave, 2500 blocks
    float ps = 0.f, pq = 0.f;
    {
        int c = cnt[i];                            // dedup'd degree
        const int* lst = nbr + (size_t)i * CAP;
        float a[6] = {0.f, 0.f, 0.f, 0.f, 0.f, 0.f};
        for (int k = lane; k < c; k += 64) {       // usually a single round
            int j = lst[k];
            const float* xj = xs + (size_t)j * 6;
            #pragma unroll
            for (int d = 0; d < 6; ++d) a[d] += xj[d];
        }
        #pragma unroll
        for (int d = 0; d < 6; ++d) {
            #pragma unroll
            for (int off = 32; off; off >>= 1) a[d] += __shfl_xor(a[d], off);
        }
        float di = dinv[i];
        if (lane < 32) {
            float s = b0[lane];
            #pragma unroll
            for (int d = 0; d < 6; ++d)
                s += (a[d] + xs[(size_t)i * 6 + d]) * di * W0[d * 32 + lane];
            h1[(size_t)i * 32 + lane] = s;
            ps = s; pq = s * s;
        }
    }
    __shared__ float ls[256], lq[256];
    ls[tid] = ps; lq[tid] = pq;
    __syncthreads();
    if (tid < 32) {
        float s = 0.f, q = 0.f;
        #pragma unroll
        for (int k = 0; k < 8; ++k) { s += ls[k * 32 + tid]; q += lq[k * 32 + tid]; }
        int shard = blockIdx.x & (SHARDS - 1);
        atomicAdd(&acc[(0 * 32 + tid) * SHARDS + shard], s);
        atomicAdd(&acc[(1 * 32 + tid) * SHARDS + shard], q);
    }
}

// ---------------- K5: BN1 affine + apply + ReLU -> hB; prescale -> hBs ----------------
__global__ void __launch_bounds__(256) bn1_apply(const float* __restrict__ h1,
                                                 const float* __restrict__ acc,
                                                 const float* __restrict__ g0,
                                                 const float* __restrict__ be0,
                                                 const float* __restrict__ dinv,
                                                 float* __restrict__ hB,
                                                 float* __restrict__ hBs) {
    __shared__ float sc[32], sh[32];
    int tid = threadIdx.x;
    if (tid < 32) {
        float S = 0.f, Q = 0.f;
        #pragma unroll
        for (int s2 = 0; s2 < SHARDS; ++s2) {
            S += acc[(0 * 32 + tid) * SHARDS + s2];
            Q += acc[(1 * 32 + tid) * SHARDS + s2];
        }
        float mu = S / (float)N_NODES;
        float var = Q / (float)N_NODES - mu * mu;  // biased
        float rstd = rsqrtf(var + BN_EPS);
        float scale = g0[tid] * rstd;
        sc[tid] = scale; sh[tid] = be0[tid] - mu * scale;
    }
    __syncthreads();
    for (int idx = blockIdx.x * 256 + tid; idx < N_NODES * 32; idx += 640 * 256) {
        int f = idx & 31;
        float v = fmaxf(h1[idx] * sc[f] + sh[f], 0.f);
        hB[idx] = v;                               // residual input
        hBs[idx] = v * dinv[idx >> 5];             // prescaled for agg2
    }
}

// ---------------- K6: agg2 (prescaled hBs, wave-uniform ILP-4) + GEMM W1 + BN2 shards ----------------
__global__ void __launch_bounds__(256) agg2_gemm_bn(const int* __restrict__ nbr,
                                                    const int* __restrict__ cnt,
                                                    const float* __restrict__ dinv,
                                                    const float* __restrict__ hBs,
                                                    const float* __restrict__ W1,
                                                    const float* __restrict__ b1,
                                                    float* __restrict__ h2,
                                                    float* __restrict__ acc) {
    int tid = threadIdx.x;
    int lane = tid & 63;
    int f = lane & 31, half = lane >> 5;
    int i = blockIdx.x * 4 + (tid >> 6);           // one row per wave, 2500 blocks
    float ps = 0.f, pq = 0.f;
    {
        int c = cnt[i];                            // dedup'd degree
        const int* lst = nbr + (size_t)i * CAP;
        int idxA = lst[lane];                      // coalesced 256B load
        int cF = c < 64 ? c : 64;                  // wave-uniform
        float a = 0.f;
        int kb = 0;
        for (; kb + 8 <= cF; kb += 8) {            // uniform trip, shfl sources active
            int j0 = __shfl(idxA, kb + half);
            int j1 = __shfl(idxA, kb + half + 2);
            int j2 = __shfl(idxA, kb + half + 4);
            int j3 = __shfl(idxA, kb + half + 6);
            float v0 = hBs[(size_t)j0 * 32 + f];
            float v1 = hBs[(size_t)j1 * 32 + f];
            float v2 = hBs[(size_t)j2 * 32 + f];
            float v3 = hBs[(size_t)j3 * 32 + f];
            a += v0 + v1 + v2 + v3;
        }
        for (int k = kb + half; k < c; k += 2)     // tail: direct loads, no cross-lane
            a += hBs[(size_t)lst[k] * 32 + f];
        a += __shfl_xor(a, 32);                    // combine halves
        float di = dinv[i];
        float t = (a + hBs[(size_t)i * 32 + f]) * di;   // + self (identity term)
        float part = 0.f;
        int fbase = half * 16;
        #pragma unroll
        for (int kk = 0; kk < 16; ++kk)
            part += __shfl(t, fbase + kk) * W1[(fbase + kk) * 32 + f];
        part += __shfl_xor(part, 32);
        if (lane < 32) {
            float sv = b1[f] + part;
            h2[(size_t)i * 32 + f] = sv;
            ps = sv; pq = sv * sv;
        }
    }
    __shared__ float ls[256], lq[256];
    ls[tid] = ps; lq[tid] = pq;
    __syncthreads();
    if (tid < 32) {
        float s = 0.f, q = 0.f;
        #pragma unroll
        for (int k = 0; k < 8; ++k) { s += ls[k * 32 + tid]; q += lq[k * 32 + tid]; }
        int shard = blockIdx.x & (SHARDS - 1);
        atomicAdd(&acc[(2 * 32 + tid) * SHARDS + shard], s);
        atomicAdd(&acc[(3 * 32 + tid) * SHARDS + shard], q);
    }
}

// ---------------- K7: BN2 affine + ReLU + residual + heads ----------------
__global__ void __launch_bounds__(256) final_fused(const float* __restrict__ hB,
                                                   const float* __restrict__ h2,
                                                   const float* __restrict__ acc,
                                                   const float* __restrict__ g1,
                                                   const float* __restrict__ be1,
                                                   const float* __restrict__ Wo,
                                                   const float* __restrict__ bo,
                                                   const float* __restrict__ Wa,
                                                   const float* __restrict__ ba,
                                                   float* __restrict__ out) {
    __shared__ float sc2[32], sh2[32];
    int tid = threadIdx.x;
    if (tid < 32) {
        float S = 0.f, Q = 0.f;
        #pragma unroll
        for (int s2 = 0; s2 < SHARDS; ++s2) {
            S += acc[(2 * 32 + tid) * SHARDS + s2];
            Q += acc[(3 * 32 + tid) * SHARDS + s2];
        }
        float mu = S / (float)N_NODES;
        float var = Q / (float)N_NODES - mu * mu;
        float rstd = rsqrtf(var + BN_EPS);
        float scale = g1[tid] * rstd;
        sc2[tid] = scale; sh2[tid] = be1[tid] - mu * scale;
    }
    __syncthreads();
    const int l = tid & 31;
    int r = (blockIdx.x * 256 + tid) >> 5;         // 1250 blocks: one row per 32-lane group
    if (r < N_NODES) {
        int idx = r * 32 + l;
        float v = hB[idx] + fmaxf(h2[idx] * sc2[l] + sh2[l], 0.f);  // residual + h_new
        float q0 = v * Wo[l * 2 + 0];
        float q1 = v * Wo[l * 2 + 1];
        float qa = v * Wa[l];
        #pragma unroll
        for (int off = 16; off; off >>= 1) {
            q0 += __shfl_xor(q0, off);
            q1 += __shfl_xor(q1, off);
            qa += __shfl_xor(qa, off);
        }
        if (l == 0) {
            out[(size_t)r * 2 + 0] = q0 + bo[0];
            out[(size_t)r * 2 + 1] = q1 + bo[1];
            out[2 * N_NODES + r] = 1.f / (1.f + expf(-(qa + ba[0])));
        }
    }
}

extern "C" void kernel_launch(void* const* d_in, const int* in_sizes, int n_in,
                              void* d_out, int out_size, void* d_ws, size_t ws_size,
                              hipStream_t stream) {
    const float* x   = (const float*)d_in[0];
    const int*  eidx = (const int*)d_in[1];
    const int E = in_sizes[1] / 2;
    const float* W0 = (const float*)d_in[2];
    const float* b0 = (const float*)d_in[3];
    const float* g0 = (const float*)d_in[4];
    const float* be0= (const float*)d_in[5];
    const float* W1 = (const float*)d_in[6];
    const float* b1 = (const float*)d_in[7];
    const float* g1 = (const float*)d_in[8];
    const float* be1= (const float*)d_in[9];
    const float* Wo = (const float*)d_in[10];
    const float* bo = (const float*)d_in[11];
    const float* Wa = (const float*)d_in[12];
    const float* ba = (const float*)d_in[13];
    float* out = (float*)d_out;

    char* ws = (char*)d_ws;
    size_t off = 0;
    auto take = [&](size_t bytes) { char* q = ws + off; off += (bytes + 255) & ~(size_t)255; return q; };
    // cnt + acc contiguous -> one tiny clear covers both (incl. padding)
    int* cnt      = (int*)take((size_t)N_NODES * 4);               // 40,192 B padded
    float* acc    = (float*)take((size_t)4 * 32 * SHARDS * 4);     // 16,384 B
    const size_t clear_bytes = 40192 + 16384;                      // 56,576 B
    int* nbr      = (int*)take((size_t)N_NODES * CAP * 4);         // 3.84 MB
    float* dinv   = (float*)take((size_t)N_NODES * 4);
    float* xs     = (float*)take((size_t)N_NODES * 6 * 4);
    float* h1     = (float*)take((size_t)N_NODES * 32 * 4);        // layer-1 pre-BN
    float* hB     = (float*)take((size_t)N_NODES * 32 * 4);        // post-BN1 (residual)
    float* hBs    = (float*)take((size_t)N_NODES * 32 * 4);        // dinv-prescaled
    float* h2     = (float*)take((size_t)N_NODES * 32 * 4);        // layer-2 pre-BN

    const int n16 = (int)(clear_bytes / 16);                       // 3536
    clear_small<<<(n16 + 255) / 256, 256, 0, stream>>>((uint4*)cnt, n16);
    scatter_append<<<(E + 255) / 256, 256, 0, stream>>>(eidx, E, cnt, nbr);
    dedup_csr<<<2500, 256, 0, stream>>>(nbr, cnt, dinv, x, xs);
    agg1_gemm_bn<<<2500, 256, 0, stream>>>(nbr, cnt, dinv, xs, W0, b0, h1, acc);
    bn1_apply<<<640, 256, 0, stream>>>(h1, acc, g0, be0, dinv, hB, hBs);
    agg2_gemm_bn<<<2500, 256, 0, stream>>>(nbr, cnt, dinv, hBs, W1, b1, h2, acc);
    final_fused<<<1250, 256, 0, stream>>>(hB, h2, acc, g1, be1, Wo, bo, Wa, ba, out);
}